// Round 9
// baseline (205.906 us; speedup 1.0000x reference)
//
#include <hip/hip_runtime.h>

// out[b] = -(x[b] . z[b])^2,  z = MLP(x): 64 ->512(ELU)->512(ELU)->256(ELU)->64
// Barrier-free K-loops: activations in LDS (in-place, read-only during K-loop),
// weights loaded per-wave straight to registers, double-buffered (no LDS pass).
// 64 rows/block, 8 waves col-split, 1024 blocks, 2 barriers/layer only.

#define DEVI __device__ __forceinline__

typedef __attribute__((ext_vector_type(4))) float f32x4;
typedef __attribute__((ext_vector_type(8))) short bf16x8;

#define PADW 520  // hb row stride 1040B -> A-reads 2-way bank alias (free, m136)
#define ROWS 64   // batch rows per block

DEVI short f2bf(float f) {  // round-to-nearest-even fp32 -> bf16 bits
  unsigned u = __float_as_uint(f);
  u = u + 0x7fffu + ((u >> 16) & 1u);
  return (short)(u >> 16);
}

// One fused conversion kernel: W1|W2|W3|W4 fp32 -> bf16 into contiguous d_ws.
__global__ void cvtw_all_kernel(const float* __restrict__ W1, const float* __restrict__ W2,
                                const float* __restrict__ W3, const float* __restrict__ W4,
                                short* __restrict__ dst) {
  int i = blockIdx.x * blockDim.x + threadIdx.x;
  if (i >= 110592) return;
  const float* src;
  int off;
  if (i < 8192)        { src = W1; off = 0; }
  else if (i < 73728)  { src = W2; off = 8192; }
  else if (i < 106496) { src = W3; off = 73728; }
  else                 { src = W4; off = 106496; }
  float4 v = reinterpret_cast<const float4*>(src)[i - off];
  short4 o;
  o.x = f2bf(v.x); o.y = f2bf(v.y); o.z = f2bf(v.z); o.w = f2bf(v.w);
  reinterpret_cast<short4*>(dst)[i] = o;
}

// Load this wave's B fragments for K-slice ks (BK=32) into registers.
template<int K, int NCT>
DEVI void loadB(bf16x8 (&b)[NCT], const short* __restrict__ Wb,
                int c0, int lr, int kg, int ks) {
#pragma unroll
  for (int ct = 0; ct < NCT; ++ct)
    b[ct] = *reinterpret_cast<const bf16x8*>(&Wb[(c0 + ct * 16 + lr) * K + ks * 32 + kg * 8]);
}

// Hidden layer: barrier-free K-loop, B double-buffered in regs, in-place hb update.
// A-frag: lane l -> row (l&15), k=(l>>4)*8+j ; D: col=lane&15, row=(lane>>4)*4+j
template<int K, int NCT>
DEVI void hidden_layer(const short* __restrict__ Wb, const float* __restrict__ bias,
                       short (&hb)[ROWS][PADW], int wid, int lr, int kg) {
  const int c0 = wid * (NCT * 16);
  constexpr int NKS = K / 32;
  f32x4 acc[4][NCT] = {};
  bf16x8 bA[NCT], bB[NCT];
  loadB<K, NCT>(bA, Wb, c0, lr, kg, 0);
  for (int ks = 0; ks < NKS; ks += 2) {
    // even step: prefetch ks+1 into bB, compute from bA
    if (ks + 1 < NKS) loadB<K, NCT>(bB, Wb, c0, lr, kg, ks + 1);
    {
      const int kk = ks * 32 + kg * 8;
      bf16x8 a[4];
#pragma unroll
      for (int rt = 0; rt < 4; ++rt)
        a[rt] = *reinterpret_cast<const bf16x8*>(&hb[rt * 16 + lr][kk]);
#pragma unroll
      for (int rt = 0; rt < 4; ++rt)
#pragma unroll
        for (int ct = 0; ct < NCT; ++ct)
          acc[rt][ct] = __builtin_amdgcn_mfma_f32_16x16x32_bf16(a[rt], bA[ct], acc[rt][ct], 0, 0, 0);
    }
    if (ks + 1 >= NKS) break;
    // odd step: prefetch ks+2 into bA, compute from bB
    if (ks + 2 < NKS) loadB<K, NCT>(bA, Wb, c0, lr, kg, ks + 2);
    {
      const int kk = (ks + 1) * 32 + kg * 8;
      bf16x8 a[4];
#pragma unroll
      for (int rt = 0; rt < 4; ++rt)
        a[rt] = *reinterpret_cast<const bf16x8*>(&hb[rt * 16 + lr][kk]);
#pragma unroll
      for (int rt = 0; rt < 4; ++rt)
#pragma unroll
        for (int ct = 0; ct < NCT; ++ct)
          acc[rt][ct] = __builtin_amdgcn_mfma_f32_16x16x32_bf16(a[rt], bB[ct], acc[rt][ct], 0, 0, 0);
    }
  }
  __syncthreads();  // all waves done reading hb before in-place overwrite
#pragma unroll
  for (int ct = 0; ct < NCT; ++ct) {
    const int col = c0 + ct * 16 + lr;
    const float bv = bias[col];
#pragma unroll
    for (int rt = 0; rt < 4; ++rt) {
#pragma unroll
      for (int j = 0; j < 4; ++j) {
        float v = acc[rt][ct][j] + bv;
        v = v > 0.f ? v : (__expf(v) - 1.f);
        hb[rt * 16 + kg * 4 + j][col] = f2bf(v);
      }
    }
  }
  __syncthreads();  // epilogue writes visible before next layer's A-reads
}

// Layer 4 (256->64, no ELU) + fused dot with fp32 x + write -(dot)^2.
// Waves 0..3: 16 rows x all 64 cols each; W4 direct from global (small, L2-hot).
DEVI void final_layer(const short* __restrict__ W4b, const float* __restrict__ b4,
                      const float* __restrict__ xg, float* __restrict__ out,
                      short (&hb)[ROWS][PADW], int wid, int lane, int R0) {
  const int lr = lane & 15, kg = lane >> 4;
  const int r0 = wid * 16;
  f32x4 acc[4] = {};
  for (int ks = 0; ks < 8; ++ks) {
    const int kk = ks * 32 + kg * 8;
    bf16x8 a = *reinterpret_cast<const bf16x8*>(&hb[r0 + lr][kk]);
#pragma unroll
    for (int ct = 0; ct < 4; ++ct) {
      bf16x8 b = *reinterpret_cast<const bf16x8*>(&W4b[(ct * 16 + lr) * 256 + kk]);
      acc[ct] = __builtin_amdgcn_mfma_f32_16x16x32_bf16(a, b, acc[ct], 0, 0, 0);
    }
  }
  float bv[4];
#pragma unroll
  for (int ct = 0; ct < 4; ++ct) bv[ct] = b4[ct * 16 + lr];
#pragma unroll
  for (int j = 0; j < 4; ++j) {
    const int gr = R0 + r0 + kg * 4 + j;  // global batch row
    float p = 0.f;
#pragma unroll
    for (int ct = 0; ct < 4; ++ct)
      p += (acc[ct][j] + bv[ct]) * xg[gr * 64 + ct * 16 + lr];
    p += __shfl_xor(p, 1);
    p += __shfl_xor(p, 2);
    p += __shfl_xor(p, 4);
    p += __shfl_xor(p, 8);
    if (lr == 0) out[gr] = -p * p;
  }
}

__global__ __launch_bounds__(512, 2)  // 256-reg budget: acc 64 + B dbuf 64 + slack
void mlp_fused_kernel(const float* __restrict__ x,
                      const short* __restrict__ Wb,
                      const float* __restrict__ b1, const float* __restrict__ b2,
                      const float* __restrict__ b3, const float* __restrict__ b4,
                      float* __restrict__ out) {
  __shared__ __align__(16) short hb[ROWS][PADW];  // 66,560 B activations only
  const int tid = threadIdx.x;
  const int lane = tid & 63, wid = tid >> 6;
  const int lr = lane & 15, kg = lane >> 4;
  const int R0 = blockIdx.x * ROWS;

  const short* W1b = Wb;
  const short* W2b = Wb + 32768;
  const short* W3b = Wb + 32768 + 262144;
  const short* W4b = Wb + 32768 + 262144 + 131072;

  // Stage x tile -> bf16 LDS [64][64] (coalesced float4 loads, 2 per thread)
#pragma unroll
  for (int s = 0; s < 2; ++s) {
    const int f = tid + s * 512;        // float4 index in tile, 0..1023
    const int r = f >> 4, c4 = f & 15;  // 16 float4 per 64-col row
    float4 v = reinterpret_cast<const float4*>(x)[R0 * 16 + f];
    short4 o;
    o.x = f2bf(v.x); o.y = f2bf(v.y); o.z = f2bf(v.z); o.w = f2bf(v.w);
    *reinterpret_cast<short4*>(&hb[r][c4 * 4]) = o;
  }
  __syncthreads();

  hidden_layer<64, 4>(W1b, b1, hb, wid, lr, kg);   // 64 -> 512, ELU
  hidden_layer<512, 4>(W2b, b2, hb, wid, lr, kg);  // 512 -> 512, ELU
  hidden_layer<512, 2>(W3b, b3, hb, wid, lr, kg);  // 512 -> 256, ELU
  if (wid < 4)
    final_layer(W4b, b4, x, out, hb, wid, lane, R0);  // 256 -> 64, dot, -p^2
}

extern "C" void kernel_launch(void* const* d_in, const int* in_sizes, int n_in,
                              void* d_out, int out_size, void* d_ws, size_t ws_size,
                              hipStream_t stream) {
  const float* x  = (const float*)d_in[0];
  const float* W1 = (const float*)d_in[1];
  const float* b1 = (const float*)d_in[2];
  const float* W2 = (const float*)d_in[3];
  const float* b2 = (const float*)d_in[4];
  const float* W3 = (const float*)d_in[5];
  const float* b3 = (const float*)d_in[6];
  const float* W4 = (const float*)d_in[7];
  const float* b4 = (const float*)d_in[8];
  float* out = (float*)d_out;
  short* wsb = (short*)d_ws;  // bf16 weights: 442368 shorts = 884736 B

  cvtw_all_kernel<<<432, 256, 0, stream>>>(W1, W2, W3, W4, wsb);
  mlp_fused_kernel<<<1024, 512, 0, stream>>>(x, wsb, b1, b2, b3, b4, out);
}